// Round 1
// baseline (1387.951 us; speedup 1.0000x reference)
//
#include <hip/hip_runtime.h>
#include <hip/hip_bf16.h>
#include <cstdint>

// Problem constants
// B=32, L=256, D=256, H=256, E=8, NL=4, K=4
// BE = B*E = 256 independent recurrent sequences.

__device__ __forceinline__ float fast_tanh(float x) {
  x = fminf(15.f, fmaxf(-15.f, x));
  float t = __expf(2.f * x);          // exp(2x); x clamped so no overflow
  return (t - 1.f) / (t + 1.f);
}

// ---------------- LayerNorm over D for each (b,l) row ----------------
__global__ __launch_bounds__(256) void ln_kernel(
    const float* __restrict__ x, const float* __restrict__ g,
    const float* __restrict__ beta, float* __restrict__ out)
{
  const int row = blockIdx.x;          // b*L + l
  const int t = threadIdx.x;           // d
  const float v = x[row * 256 + t];
  __shared__ float red[4];
  float s = v;
  #pragma unroll
  for (int off = 32; off > 0; off >>= 1) s += __shfl_xor(s, off);
  if ((t & 63) == 0) red[t >> 6] = s;
  __syncthreads();
  const float mean = (red[0] + red[1] + red[2] + red[3]) * (1.f / 256.f);
  const float d = v - mean;
  float sq = d * d;
  #pragma unroll
  for (int off = 32; off > 0; off >>= 1) sq += __shfl_xor(sq, off);
  __syncthreads();                     // all mean-reads done before red reuse
  if ((t & 63) == 0) red[t >> 6] = sq;
  __syncthreads();
  const float var = (red[0] + red[1] + red[2] + red[3]) * (1.f / 256.f);
  out[row * 256 + t] = d * rsqrtf(var + 1e-5f) * g[t] + beta[t];
}

// ---------------- Depthwise causal conv1d (K=4, left pad 3) ----------------
__global__ __launch_bounds__(256) void conv_kernel(
    const float* __restrict__ ln, const float* __restrict__ w,
    const float* __restrict__ cb, float* __restrict__ out)
{
  const int l = blockIdx.x & 255;
  const int b = blockIdx.x >> 8;
  const int d = threadIdx.x;
  const float4 wv = *(const float4*)(w + d * 4);   // conv_w[d,0,0..3]
  const float wk[4] = {wv.x, wv.y, wv.z, wv.w};
  float acc = cb[d];
  #pragma unroll
  for (int k = 0; k < 4; ++k) {
    const int ls = l - 3 + k;                      // out[l] = sum_k w[k]*in[l-3+k]
    if (ls >= 0) acc = fmaf(ln[((b << 8) + ls) * 256 + d], wk[k], acc);
  }
  out[((b << 8) + l) * 256 + d] = acc;
}

// ---------------- Input GEMM: pre = s_e * ((in * r_e) @ W_ih^T) + bias -------
// mode 0: in = conv (B*L,256), row m=(b*E+e)*L+l maps to conv row (b,l).
// mode 1: in = prev layer ys (65536,256), row m direct.
// Grid: x = N-tiles (4), y = M-tiles (1024); 256 threads; 64x64 tile, 4x4/thread.
__global__ __launch_bounds__(256) void gemm_kernel(
    const float* __restrict__ A, const float* __restrict__ W,
    const float* __restrict__ rl, const float* __restrict__ sl,
    const float* __restrict__ bias, float* __restrict__ out, int mode)
{
  __shared__ __align__(16) float As[16 * 64];
  __shared__ __align__(16) float Bs[16 * 64];
  const int n0 = blockIdx.x * 64;
  const int m0 = blockIdx.y * 64;
  const int t = threadIdx.x;
  const int e = (m0 >> 8) & 7;                 // block-uniform (64 | L)
  const float* rrow = rl + (e << 8);
  const float* Abase;
  if (mode == 0) {
    const int b = m0 >> 11;
    const int l0 = m0 & 255;
    Abase = A + (size_t)((b << 8) + l0) * 256;
  } else {
    Abase = A + (size_t)m0 * 256;
  }
  const int lr = t >> 2;                       // 0..63 row/col within tile
  const int lk = (t & 3) << 2;                 // 0,4,8,12
  const int tx = t & 15, ty = t >> 4;
  float acc[4][4] = {};
  for (int k0 = 0; k0 < 256; k0 += 16) {
    float4 av = *(const float4*)(Abase + (size_t)lr * 256 + k0 + lk);
    const float4 rv = *(const float4*)(rrow + k0 + lk);
    av.x *= rv.x; av.y *= rv.y; av.z *= rv.z; av.w *= rv.w;
    const float4 wv = *(const float4*)(W + (size_t)(n0 + lr) * 256 + k0 + lk);
    __syncthreads();                           // prior-iter LDS reads done
    As[(lk + 0) * 64 + lr] = av.x; As[(lk + 1) * 64 + lr] = av.y;
    As[(lk + 2) * 64 + lr] = av.z; As[(lk + 3) * 64 + lr] = av.w;
    Bs[(lk + 0) * 64 + lr] = wv.x; Bs[(lk + 1) * 64 + lr] = wv.y;
    Bs[(lk + 2) * 64 + lr] = wv.z; Bs[(lk + 3) * 64 + lr] = wv.w;
    __syncthreads();
    #pragma unroll
    for (int kk = 0; kk < 16; ++kk) {
      const float4 a4 = *(const float4*)(As + kk * 64 + (ty << 2));
      const float4 b4 = *(const float4*)(Bs + kk * 64 + (tx << 2));
      const float av4[4] = {a4.x, a4.y, a4.z, a4.w};
      const float bv4[4] = {b4.x, b4.y, b4.z, b4.w};
      #pragma unroll
      for (int i = 0; i < 4; ++i)
        #pragma unroll
        for (int j = 0; j < 4; ++j)
          acc[i][j] = fmaf(av4[i], bv4[j], acc[i][j]);
    }
  }
  const float4 s4 = *(const float4*)(sl + (e << 8) + n0 + (tx << 2));
  const float4 bb4 = *(const float4*)(bias + n0 + (tx << 2));
  const float sv[4] = {s4.x, s4.y, s4.z, s4.w};
  const float bv[4] = {bb4.x, bb4.y, bb4.z, bb4.w};
  #pragma unroll
  for (int i = 0; i < 4; ++i) {
    float4 o;
    o.x = fmaf(acc[i][0], sv[0], bv[0]);
    o.y = fmaf(acc[i][1], sv[1], bv[1]);
    o.z = fmaf(acc[i][2], sv[2], bv[2]);
    o.w = fmaf(acc[i][3], sv[3], bv[3]);
    *(float4*)(out + (size_t)(m0 + (ty << 2) + i) * 256 + n0 + (tx << 2)) = o;
  }
}

// ---------------- Recurrent scan: h_t = tanh(pre_t + W_hh @ h_{t-1}) --------
// One block per (b,e). 1024 threads: t = c*256 + k; thread holds W_hh[k, 64c:64c+64]
// in VGPRs. h in LDS; 4 partials per k reduced through LDS. In-place: P holds
// pre on input, ys on output.
__global__ __launch_bounds__(1024) void rnn_kernel(
    float* __restrict__ P, const float* __restrict__ Whh,
    float* __restrict__ hlast)
{
  __shared__ __align__(16) float hbuf[256];
  __shared__ float part[1024];
  const int be = blockIdx.x;
  float* Pb = P + (size_t)be * 256 * 256;
  const int t = threadIdx.x;
  const int k = t & 255;
  const int c = t >> 8;                        // wave-uniform chunk
  float4 w[16];
  const float4* Wv = (const float4*)(Whh + (size_t)k * 256 + (c << 6));
  #pragma unroll
  for (int j = 0; j < 16; ++j) w[j] = Wv[j];
  if (t < 256) hbuf[t] = 0.f;
  float pv = (t < 256) ? Pb[t] : 0.f;          // pre for l=0
  __syncthreads();
  for (int l = 0; l < 256; ++l) {
    const float4* hv4 = (const float4*)(hbuf + (c << 6));
    float partial = 0.f;
    #pragma unroll
    for (int j = 0; j < 16; ++j) {             // broadcast LDS reads
      const float4 hv = hv4[j];
      partial = fmaf(w[j].x, hv.x, partial);
      partial = fmaf(w[j].y, hv.y, partial);
      partial = fmaf(w[j].z, hv.z, partial);
      partial = fmaf(w[j].w, hv.w, partial);
    }
    part[(c << 8) + k] = partial;
    float pv_next = 0.f;
    if (t < 256 && l < 255) pv_next = Pb[(size_t)(l + 1) * 256 + t]; // prefetch
    __syncthreads();
    if (t < 256) {                             // waves 0-3: one per SIMD
      const float sum = part[t] + part[256 + t] + part[512 + t] + part[768 + t] + pv;
      const float hn = fast_tanh(sum);
      hbuf[t] = hn;
      Pb[(size_t)l * 256 + t] = hn;            // ys overwrites pre in place
    }
    pv = pv_next;
    __syncthreads();
  }
  if (hlast != nullptr && t < 256) hlast[(size_t)be * 256 + t] = hbuf[t];
}

extern "C" void kernel_launch(void* const* d_in, const int* in_sizes, int n_in,
                              void* d_out, int out_size, void* d_ws, size_t ws_size,
                              hipStream_t stream) {
  const float* x      = (const float*)d_in[0];
  const float* conv_w = (const float*)d_in[1];
  const float* conv_b = (const float*)d_in[2];
  const float* ln_g   = (const float*)d_in[3];
  const float* ln_b   = (const float*)d_in[4];
  const float* W_ih   = (const float*)d_in[5];   // (4,256,256)
  const float* W_hh   = (const float*)d_in[6];   // (4,256,256)
  const float* r      = (const float*)d_in[7];   // (4,8,256)
  const float* s      = (const float*)d_in[8];   // (4,8,256)
  const float* bb     = (const float*)d_in[9];   // (4,256)

  float* outh = (float*)d_out;                   // (B,E,L,H) = 16,777,216 floats
  float* outl = outh + 16777216;                 // (B,E,H)   = 65,536 floats

  float* P0  = (float*)d_ws;                     // 64 MiB ping buffer
  float* lnb = outh;                             // LN scratch inside d_out (overwritten later)
  float* cvb = outh + 2097152;                   // conv scratch inside d_out

  ln_kernel<<<8192, 256, 0, stream>>>(x, ln_g, ln_b, lnb);
  conv_kernel<<<8192, 256, 0, stream>>>(lnb, conv_w, conv_b, cvb);

  const dim3 ggrid(4, 1024, 1);
  // layer 0: conv -> P0 (pre), rnn in place
  gemm_kernel<<<ggrid, 256, 0, stream>>>(cvb, W_ih, r, s, bb, P0, 0);
  rnn_kernel<<<256, 1024, 0, stream>>>(P0, W_hh, nullptr);
  // layer 1: P0 -> outh
  gemm_kernel<<<ggrid, 256, 0, stream>>>(P0, W_ih + 65536, r + 2048, s + 2048, bb + 256, outh, 1);
  rnn_kernel<<<256, 1024, 0, stream>>>(outh, W_hh + 65536, nullptr);
  // layer 2: outh -> P0
  gemm_kernel<<<ggrid, 256, 0, stream>>>(outh, W_ih + 131072, r + 4096, s + 4096, bb + 512, P0, 1);
  rnn_kernel<<<256, 1024, 0, stream>>>(P0, W_hh + 131072, nullptr);
  // layer 3: P0 -> outh (final), rnn writes h and h_last
  gemm_kernel<<<ggrid, 256, 0, stream>>>(P0, W_ih + 196608, r + 6144, s + 6144, bb + 768, outh, 1);
  rnn_kernel<<<256, 1024, 0, stream>>>(outh, W_hh + 196608, outl);
}